// Round 2
// baseline (347.732 us; speedup 1.0000x reference)
//
#include <hip/hip_runtime.h>
#include <hip/hip_bf16.h>
#include <stdint.h>

#define MM 100000   // rows in messages / idx
#define NN 200000   // rows in S / out
#define DD 128      // feature dim
#define BM 16       // message rows per block (100000 = 6250 * 16, no tail)

typedef __attribute__((ext_vector_type(8))) short short8;
typedef __attribute__((ext_vector_type(4))) float f32x4;
typedef __attribute__((ext_vector_type(4))) unsigned short u16x4;

__device__ __forceinline__ unsigned short f2bf(float f) {
    union { float f; uint32_t u; } v; v.f = f;
    return (unsigned short)((v.u + 0x7FFFu + ((v.u >> 16) & 1u)) >> 16);  // RNE
}
__device__ __forceinline__ float bf2f(unsigned short s) {
    union { uint32_t u; float f; } v; v.u = ((uint32_t)s) << 16;
    return v.f;
}
__device__ __forceinline__ float sigmoidf(float x) {
    return 1.0f / (1.0f + __expf(-x));
}
__device__ __forceinline__ float tanh_fast(float x) {
    return 2.0f / (1.0f + __expf(-2.0f * x)) - 1.0f;
}

// ---------- ones-fill machinery ----------
__global__ void fill_ones(f32x4* __restrict__ out, int n4) {
    int i = blockIdx.x * blockDim.x + threadIdx.x;
    int stride = gridDim.x * blockDim.x;
    f32x4 ones = {1.f, 1.f, 1.f, 1.f};
    for (; i < n4; i += stride) out[i] = ones;
}

__global__ void clear_mark(uint32_t* __restrict__ mark32) {
    int i = blockIdx.x * blockDim.x + threadIdx.x;
    if (i < NN / 4) mark32[i] = 0;
}

__global__ void mark_rows(const int* __restrict__ idx, uint8_t* __restrict__ mark) {
    int m = blockIdx.x * blockDim.x + threadIdx.x;
    if (m < MM) mark[idx[m]] = 1;
}

__global__ void fill_unmarked(const uint8_t* __restrict__ mark, f32x4* __restrict__ out4) {
    int i = blockIdx.x * blockDim.x + threadIdx.x;
    int stride = gridDim.x * blockDim.x;
    f32x4 ones = {1.f, 1.f, 1.f, 1.f};
    for (; i < NN * 32; i += stride)
        if (!mark[i >> 5]) out4[i] = ones;
}

__global__ void conv_w(const float* __restrict__ wih, const float* __restrict__ whh,
                       unsigned short* __restrict__ dst) {
    int i = blockIdx.x * blockDim.x + threadIdx.x;
    if (i < 3 * DD * DD) {
        dst[i] = f2bf(wih[i]);
        dst[3 * DD * DD + i] = f2bf(whh[i]);
    }
}

template <bool WBF16>
__device__ __forceinline__ short8 load_wfrag(const void* W, int row, int kbase) {
    if constexpr (WBF16) {
        const unsigned short* p = (const unsigned short*)W;
        return *reinterpret_cast<const short8*>(p + (size_t)row * DD + kbase);
    } else {
        const float* p = (const float*)W + (size_t)row * DD + kbase;
        f32x4 a = *reinterpret_cast<const f32x4*>(p);
        f32x4 b = *reinterpret_cast<const f32x4*>(p + 4);
        short8 r;
        r[0] = (short)f2bf(a[0]); r[1] = (short)f2bf(a[1]);
        r[2] = (short)f2bf(a[2]); r[3] = (short)f2bf(a[3]);
        r[4] = (short)f2bf(b[0]); r[5] = (short)f2bf(b[1]);
        r[6] = (short)f2bf(b[2]); r[7] = (short)f2bf(b[3]);
        return r;
    }
}

// 512 threads = 8 waves; each wave owns 16 output columns for all BM=16 rows.
// Accumulators: r and z gates sum gi+gh directly (same acc), only n-gate
// keeps gi_n / gh_n separate -> 4 f32x4 acc per lane (16 VGPRs, was 96).
// __launch_bounds__(512,8) forces <=64 VGPR -> 8 waves/SIMD -> 4 blocks/CU.
template <bool WBF16>
__global__ __launch_bounds__(512, 8) void gru_kernel(
    const float* __restrict__ msgs, const float* __restrict__ S,
    const void* __restrict__ Wih, const void* __restrict__ Whh,
    const float* __restrict__ b_ih, const float* __restrict__ b_hh,
    const int* __restrict__ idx, float* __restrict__ out)
{
    __shared__ unsigned short Xl[BM][136];
    __shared__ unsigned short Hl[BM][136];
    __shared__ int Il[BM];

    const int tid = threadIdx.x;
    const int mbase = blockIdx.x * BM;

    // ---- stage: 16 rows x 32 f32x4-chunks = 512 tasks, one per thread ----
    {
        int row = tid >> 5, ch = tid & 31;
        int m = mbase + row;                      // grid is exact: m < MM always
        int si = idx[m];
        f32x4 xv = *reinterpret_cast<const f32x4*>(msgs + (size_t)m * DD + ch * 4);
        f32x4 hv = *reinterpret_cast<const f32x4*>(S + (size_t)si * DD + ch * 4);
        u16x4 xb, hb;
        #pragma unroll
        for (int j = 0; j < 4; ++j) { xb[j] = f2bf(xv[j]); hb[j] = f2bf(hv[j]); }
        *reinterpret_cast<u16x4*>(&Xl[row][ch * 4]) = xb;
        *reinterpret_cast<u16x4*>(&Hl[row][ch * 4]) = hb;
        if (ch == 0) Il[row] = si;
    }
    __syncthreads();

    const int wave = tid >> 6;
    const int lane = tid & 63;
    const int l15 = lane & 15;
    const int lk = lane >> 4;
    const int cbase = wave * 16;                  // this wave's 16 output columns

    f32x4 accR = {0.f, 0.f, 0.f, 0.f};           // gi_r + gh_r
    f32x4 accZ = {0.f, 0.f, 0.f, 0.f};           // gi_z + gh_z
    f32x4 accNi = {0.f, 0.f, 0.f, 0.f};          // gi_n
    f32x4 accNh = {0.f, 0.f, 0.f, 0.f};          // gh_n

    const int wrow = cbase + l15;                 // W row = output column (gate 0)

    #pragma unroll
    for (int ks = 0; ks < 4; ++ks) {              // K = 128 in 4 steps of 32
        const int kb = ks * 32 + lk * 8;
        short8 ax = *reinterpret_cast<const short8*>(&Xl[l15][kb]);
        short8 ah = *reinterpret_cast<const short8*>(&Hl[l15][kb]);

        short8 bRi = load_wfrag<WBF16>(Wih, wrow, kb);
        short8 bRh = load_wfrag<WBF16>(Whh, wrow, kb);
        accR = __builtin_amdgcn_mfma_f32_16x16x32_bf16(ax, bRi, accR, 0, 0, 0);
        accR = __builtin_amdgcn_mfma_f32_16x16x32_bf16(ah, bRh, accR, 0, 0, 0);

        short8 bZi = load_wfrag<WBF16>(Wih, DD + wrow, kb);
        short8 bZh = load_wfrag<WBF16>(Whh, DD + wrow, kb);
        accZ = __builtin_amdgcn_mfma_f32_16x16x32_bf16(ax, bZi, accZ, 0, 0, 0);
        accZ = __builtin_amdgcn_mfma_f32_16x16x32_bf16(ah, bZh, accZ, 0, 0, 0);

        short8 bNi = load_wfrag<WBF16>(Wih, 2 * DD + wrow, kb);
        short8 bNh = load_wfrag<WBF16>(Whh, 2 * DD + wrow, kb);
        accNi = __builtin_amdgcn_mfma_f32_16x16x32_bf16(ax, bNi, accNi, 0, 0, 0);
        accNh = __builtin_amdgcn_mfma_f32_16x16x32_bf16(ah, bNh, accNh, 0, 0, 0);
    }

    // ---- epilogue: gates + scatter ----
    const int c = cbase + l15;                    // 0..127
    const float br = b_ih[c] + b_hh[c];
    const float bz = b_ih[DD + c] + b_hh[DD + c];
    const float bin_ = b_ih[2 * DD + c];
    const float bhn = b_hh[2 * DD + c];
    #pragma unroll
    for (int j = 0; j < 4; ++j) {
        int mloc = lk * 4 + j;                    // C/D: row=(lane>>4)*4+reg [m89]
        float r = sigmoidf(accR[j] + br);
        float z = sigmoidf(accZ[j] + bz);
        float n = tanh_fast(accNi[j] + bin_ + r * (accNh[j] + bhn));
        float h = bf2f(Hl[mloc][c]);
        int o = Il[mloc];
        out[(size_t)o * DD + c] = (1.f - z) * n + z * h;
    }
}

extern "C" void kernel_launch(void* const* d_in, const int* in_sizes, int n_in,
                              void* d_out, int out_size, void* d_ws, size_t ws_size,
                              hipStream_t stream) {
    const float* msgs  = (const float*)d_in[0];
    const float* S     = (const float*)d_in[1];
    const float* W_ih  = (const float*)d_in[2];
    const float* W_hh  = (const float*)d_in[3];
    const float* b_ih  = (const float*)d_in[4];
    const float* b_hh  = (const float*)d_in[5];
    const int*   idx   = (const int*)d_in[6];
    float* out = (float*)d_out;

    const int blocks = MM / BM;                       // 6250, exact
    const size_t wbytes = (size_t)2 * 3 * DD * DD * sizeof(unsigned short); // 196608
    const size_t need = wbytes + NN + 256;            // weights + row mask

    if (ws_size >= need) {
        unsigned short* wbf = (unsigned short*)d_ws;
        uint8_t* mark = (uint8_t*)d_ws + wbytes;
        // mask-based ones fill: write ones ONLY to non-updated rows (51 MB not 102)
        clear_mark<<<(NN / 4 + 511) / 512, 512, 0, stream>>>((uint32_t*)mark);
        mark_rows<<<(MM + 511) / 512, 512, 0, stream>>>(idx, mark);
        conv_w<<<(3 * DD * DD + 255) / 256, 256, 0, stream>>>(W_ih, W_hh, wbf);
        gru_kernel<true><<<blocks, 512, 0, stream>>>(msgs, S, wbf, wbf + 3 * DD * DD,
                                                     b_ih, b_hh, idx, out);
        fill_unmarked<<<2048, 256, 0, stream>>>(mark, (f32x4*)out);
    } else {
        fill_ones<<<2048, 256, 0, stream>>>((f32x4*)out, NN * DD / 4);
        gru_kernel<false><<<blocks, 512, 0, stream>>>(msgs, S, W_ih, W_hh,
                                                      b_ih, b_hh, idx, out);
    }
}

// Round 3
// 254.172 us; speedup vs baseline: 1.3681x; 1.3681x over previous
//
#include <hip/hip_runtime.h>
#include <hip/hip_bf16.h>
#include <stdint.h>

#define MM 100000   // rows in messages / idx
#define NN 200000   // rows in S / out
#define DD 128      // feature dim
#define BM 64       // message rows per tile
#define NT 1563     // ceil(MM/BM); last tile has 32 valid rows
#define GRID 256    // persistent blocks (1/CU), grid-stride over tiles

typedef __attribute__((ext_vector_type(8))) short short8;
typedef __attribute__((ext_vector_type(4))) float f32x4;
typedef __attribute__((ext_vector_type(4))) unsigned short u16x4;

__device__ __forceinline__ unsigned short f2bf(float f) {
    union { float f; uint32_t u; } v; v.f = f;
    return (unsigned short)((v.u + 0x7FFFu + ((v.u >> 16) & 1u)) >> 16);  // RNE
}
__device__ __forceinline__ float bf2f(unsigned short s) {
    union { uint32_t u; float f; } v; v.u = ((uint32_t)s) << 16;
    return v.f;
}
__device__ __forceinline__ float sigmoidf(float x) {
    return 1.0f / (1.0f + __expf(-x));
}
__device__ __forceinline__ float tanh_fast(float x) {
    return 2.0f / (1.0f + __expf(-2.0f * x)) - 1.0f;
}

__global__ void fill_ones(f32x4* __restrict__ out, int n4) {
    int i = blockIdx.x * blockDim.x + threadIdx.x;
    int stride = gridDim.x * blockDim.x;
    f32x4 ones = {1.f, 1.f, 1.f, 1.f};
    for (; i < n4; i += stride) out[i] = ones;
}

__global__ void conv_w(const float* __restrict__ wih, const float* __restrict__ whh,
                       unsigned short* __restrict__ dst) {
    int i = blockIdx.x * blockDim.x + threadIdx.x;
    if (i < 3 * DD * DD) {
        dst[i] = f2bf(wih[i]);
        dst[3 * DD * DD + i] = f2bf(whh[i]);
    }
}

template <bool WBF16>
__device__ __forceinline__ short8 load_wfrag(const void* W, int row, int kbase) {
    if constexpr (WBF16) {
        const unsigned short* p = (const unsigned short*)W;
        return *reinterpret_cast<const short8*>(p + (size_t)row * DD + kbase);
    } else {
        const float* p = (const float*)W + (size_t)row * DD + kbase;
        f32x4 a = *reinterpret_cast<const f32x4*>(p);
        f32x4 b = *reinterpret_cast<const f32x4*>(p + 4);
        short8 r;
        r[0] = (short)f2bf(a[0]); r[1] = (short)f2bf(a[1]);
        r[2] = (short)f2bf(a[2]); r[3] = (short)f2bf(a[3]);
        r[4] = (short)f2bf(b[0]); r[5] = (short)f2bf(b[1]);
        r[6] = (short)f2bf(b[2]); r[7] = (short)f2bf(b[3]);
        return r;
    }
}

// Persistent pipelined GRU:
//  - 512 threads = 8 waves, wave w owns output cols [16w,16w+16), all 64 rows (mt=4)
//  - grid-stride over 1563 row-tiles; per iter: stage regs->LDS(buf p), barrier,
//    ISSUE next tile's gather (hides ~900cy HBM latency under compute),
//    4 ks-steps x {6 batched weight loads (1:4 amortized), 24 MFMA}, epilogue+scatter.
//  - double-buffered LDS => ONE barrier/iter (per-wave LDS ordering covers the rest)
template <bool WBF16>
__global__ __launch_bounds__(512, 2) void gru_kernel(
    const float* __restrict__ msgs, const float* __restrict__ S,
    const void* __restrict__ Wih, const void* __restrict__ Whh,
    const float* __restrict__ b_ih, const float* __restrict__ b_hh,
    const int* __restrict__ idx, float* __restrict__ out)
{
    __shared__ unsigned short Xl[2][BM][136];
    __shared__ unsigned short Hl[2][BM][136];
    __shared__ int Il[2][BM];

    const int tid = threadIdx.x;
    const int wave = tid >> 6;
    const int lane = tid & 63;
    const int l15 = lane & 15;
    const int lk  = lane >> 4;
    const int c   = wave * 16 + l15;          // this lane's output column

    // biases hoisted (tile-invariant)
    const float br   = b_ih[c] + b_hh[c];
    const float bz   = b_ih[DD + c] + b_hh[DD + c];
    const float bn_i = b_ih[2 * DD + c];
    const float bn_h = b_hh[2 * DD + c];

    // staging role: thread covers rows {srow, srow+16, srow+32, srow+48}, chunk sch
    const int srow = tid >> 5;                // 0..15
    const int sch  = tid & 31;                // 0..31

    int t = blockIdx.x;

    // ---------------- prologue: gather tile t into regs, prefetch idx(t+GRID) ----
    int si_g[4];                              // idx for tile about to be staged
    int si_n[4];                              // idx for the tile after that (in flight)
    f32x4 px[4], ph[4];
    #pragma unroll
    for (int it = 0; it < 4; ++it) {
        int m = t * BM + srow + it * 16;
        int mm = m < MM ? m : MM - 1;         // clamp: tail-tile rows masked at store
        si_g[it] = idx[mm];
    }
    #pragma unroll
    for (int it = 0; it < 4; ++it) {
        int m = t * BM + srow + it * 16;
        int mm = m < MM ? m : MM - 1;
        px[it] = *reinterpret_cast<const f32x4*>(msgs + (size_t)mm * DD + sch * 4);
        ph[it] = *reinterpret_cast<const f32x4*>(S + (size_t)si_g[it] * DD + sch * 4);
    }
    if (t + GRID < NT) {
        #pragma unroll
        for (int it = 0; it < 4; ++it) {
            int m = (t + GRID) * BM + srow + it * 16;
            int mm = m < MM ? m : MM - 1;
            si_n[it] = idx[mm];
        }
    }

    int p = 0;
    for (; t < NT; t += GRID) {
        const bool hasn = (t + GRID) < NT;    // block-uniform

        // ---- stage current tile (regs -> LDS buf p), bf16 convert ----
        #pragma unroll
        for (int it = 0; it < 4; ++it) {
            u16x4 xb, hb;
            #pragma unroll
            for (int j = 0; j < 4; ++j) { xb[j] = f2bf(px[it][j]); hb[j] = f2bf(ph[it][j]); }
            *reinterpret_cast<u16x4*>(&Xl[p][srow + it * 16][sch * 4]) = xb;
            *reinterpret_cast<u16x4*>(&Hl[p][srow + it * 16][sch * 4]) = hb;
            if (sch == 0) Il[p][srow + it * 16] = si_g[it];
        }
        __syncthreads();

        // ---- issue NEXT tile's gather now; latency hides under compute below ----
        if (hasn) {
            #pragma unroll
            for (int it = 0; it < 4; ++it) {
                int m = (t + GRID) * BM + srow + it * 16;
                int mm = m < MM ? m : MM - 1;
                px[it] = *reinterpret_cast<const f32x4*>(msgs + (size_t)mm * DD + sch * 4);
                ph[it] = *reinterpret_cast<const f32x4*>(S + (size_t)si_n[it] * DD + sch * 4);
                si_g[it] = si_n[it];
            }
            if (t + 2 * GRID < NT) {
                #pragma unroll
                for (int it = 0; it < 4; ++it) {
                    int m = (t + 2 * GRID) * BM + srow + it * 16;
                    int mm = m < MM ? m : MM - 1;
                    si_n[it] = idx[mm];
                }
            }
        }

        // ---- compute: K=128 in 4 steps; weights batched, amortized over mt=4 ----
        f32x4 accR[4], accZ[4], accNi[4], accNh[4];
        #pragma unroll
        for (int mt = 0; mt < 4; ++mt) {
            accR[mt] = (f32x4){0.f, 0.f, 0.f, 0.f};
            accZ[mt] = (f32x4){0.f, 0.f, 0.f, 0.f};
            accNi[mt] = (f32x4){0.f, 0.f, 0.f, 0.f};
            accNh[mt] = (f32x4){0.f, 0.f, 0.f, 0.f};
        }
        #pragma unroll
        for (int ks = 0; ks < 4; ++ks) {
            const int kb = ks * 32 + lk * 8;
            short8 ax[4], ah[4];
            #pragma unroll
            for (int mt = 0; mt < 4; ++mt) {
                ax[mt] = *reinterpret_cast<const short8*>(&Xl[p][mt * 16 + l15][kb]);
                ah[mt] = *reinterpret_cast<const short8*>(&Hl[p][mt * 16 + l15][kb]);
            }
            short8 bRi = load_wfrag<WBF16>(Wih, c, kb);
            short8 bRh = load_wfrag<WBF16>(Whh, c, kb);
            short8 bZi = load_wfrag<WBF16>(Wih, DD + c, kb);
            short8 bZh = load_wfrag<WBF16>(Whh, DD + c, kb);
            short8 bNi = load_wfrag<WBF16>(Wih, 2 * DD + c, kb);
            short8 bNh = load_wfrag<WBF16>(Whh, 2 * DD + c, kb);
            #pragma unroll
            for (int mt = 0; mt < 4; ++mt) {
                accR[mt]  = __builtin_amdgcn_mfma_f32_16x16x32_bf16(ax[mt], bRi, accR[mt], 0, 0, 0);
                accR[mt]  = __builtin_amdgcn_mfma_f32_16x16x32_bf16(ah[mt], bRh, accR[mt], 0, 0, 0);
                accZ[mt]  = __builtin_amdgcn_mfma_f32_16x16x32_bf16(ax[mt], bZi, accZ[mt], 0, 0, 0);
                accZ[mt]  = __builtin_amdgcn_mfma_f32_16x16x32_bf16(ah[mt], bZh, accZ[mt], 0, 0, 0);
                accNi[mt] = __builtin_amdgcn_mfma_f32_16x16x32_bf16(ax[mt], bNi, accNi[mt], 0, 0, 0);
                accNh[mt] = __builtin_amdgcn_mfma_f32_16x16x32_bf16(ah[mt], bNh, accNh[mt], 0, 0, 0);
            }
        }

        // ---- epilogue: gates + scatter (C/D: col=lane&15, row=(lane>>4)*4+j) ----
        const int mb = t * BM;
        #pragma unroll
        for (int mt = 0; mt < 4; ++mt) {
            #pragma unroll
            for (int j = 0; j < 4; ++j) {
                int mloc = mt * 16 + lk * 4 + j;
                int m = mb + mloc;
                if (m < MM) {
                    float r = sigmoidf(accR[mt][j] + br);
                    float z = sigmoidf(accZ[mt][j] + bz);
                    float n = tanh_fast(accNi[mt][j] + bn_i + r * (accNh[mt][j] + bn_h));
                    float h = bf2f(Hl[p][mloc][c]);
                    out[(size_t)Il[p][mloc] * DD + c] = (1.f - z) * n + z * h;
                }
            }
        }
        p ^= 1;
        // no second barrier: dbuf + per-wave in-order LDS + next iter's barrier
        // protect buf reuse (write(t+2,p) is ordered after every wave's read(t,p))
    }
}

extern "C" void kernel_launch(void* const* d_in, const int* in_sizes, int n_in,
                              void* d_out, int out_size, void* d_ws, size_t ws_size,
                              hipStream_t stream) {
    const float* msgs  = (const float*)d_in[0];
    const float* S     = (const float*)d_in[1];
    const float* W_ih  = (const float*)d_in[2];
    const float* W_hh  = (const float*)d_in[3];
    const float* b_ih  = (const float*)d_in[4];
    const float* b_hh  = (const float*)d_in[5];
    const int*   idx   = (const int*)d_in[6];
    float* out = (float*)d_out;

    // ones everywhere first; gru overwrites the 100K updated rows
    fill_ones<<<2048, 256, 0, stream>>>((f32x4*)out, NN * DD / 4);

    const size_t wbytes = (size_t)2 * 3 * DD * DD * sizeof(unsigned short); // 196608
    if (ws_size >= wbytes) {
        unsigned short* wbf = (unsigned short*)d_ws;
        conv_w<<<(3 * DD * DD + 255) / 256, 256, 0, stream>>>(W_ih, W_hh, wbf);
        gru_kernel<true><<<GRID, 512, 0, stream>>>(msgs, S, wbf, wbf + 3 * DD * DD,
                                                   b_ih, b_hh, idx, out);
    } else {
        gru_kernel<false><<<GRID, 512, 0, stream>>>(msgs, S, W_ih, W_hh,
                                                    b_ih, b_hh, idx, out);
    }
}